// Round 9
// baseline (201.207 us; speedup 1.0000x reference)
//
#include <hip/hip_runtime.h>
#include <hip/hip_bf16.h>
#include <math.h>

// Problem constants: B=32, U=4096, K=4, N=2, K2=2, STRIDE=2048, UN=2048
// ws: (2, 4, 2048, 8192) f32 = 512 MB  -> the traffic floor
// GEMM per j: (32 x 8192) @ (8192 x 8192), f32 vector-FMA (no fp32 MFMA on CDNA4)
//
// d_out layout (flat, return order):
//   x_out  [0,      131072)   (32,4096)
//   new_hs [131072, 393216)   (2,2,32,2048)
//   new_c  [393216, 917504)   (2,4,32,2048)
//
// d_ws layout:
//   in_t2   at byte 0    : 2*4*8192*8 f32 = 2 MB        (in_t2[j][w][k][b'], b = w*8+b')
//   partial at byte 2 MB : 2*32*32*8192 bf16 = 33.5 MB  (partial[j][s][b][f], bf16)

#define IN_T_ELEMS (2 * 4 * 8192 * 8)
#define NSPLIT 32

typedef unsigned short ushort_t;
typedef unsigned int uint_t;

// tid enumerates output order: b'=tid&7, k=(tid>>3)&8191, w=(tid>>16)&3, j=tid>>18.
__global__ __launch_bounds__(256) void transpose_in(const float* __restrict__ x,
                                                    const float* __restrict__ hs,
                                                    float* __restrict__ in_t2) {
    int tid = blockIdx.x * 256 + threadIdx.x;   // [0, 524288)
    int bp  = tid & 7;
    int k   = (tid >> 3) & 8191;
    int w   = (tid >> 16) & 3;
    int j   = tid >> 18;
    int b   = w * 8 + bp;
    float v;
    if (k < 4096) {
        v = x[b * 4096 + k];                          // x_chunks[b][kk][d] = x[b][k]
    } else {
        int kk = k >> 11;                             // 2 or 3
        int d  = k & 2047;
        v = hs[((j * 2 + (kk - 2)) * 32 + b) * 2048 + d];   // hs (2,2,32,2048)
    }
    in_t2[tid] = v;
}

__device__ __forceinline__ ushort_t f2bf(float x) {
    __hip_bfloat16 h = __float2bfloat16(x);           // round-to-nearest
    return *reinterpret_cast<ushort_t*>(&h);
}

// Two rows of FMA: av (8 uniform batch values from LDS) x lane's 8 f-columns.
__device__ __forceinline__ void fma2(float acc[8][8], const float (*it)[8], int r,
                                     const float4* W) {
#pragma unroll
    for (int rr = 0; rr < 2; ++rr) {
        float4 a0 = *(const float4*)&it[r + rr][0];
        float4 a1 = *(const float4*)&it[r + rr][4];
        float4 w0 = W[rr * 2];
        float4 w1 = W[rr * 2 + 1];
        float av[8] = {a0.x, a0.y, a0.z, a0.w, a1.x, a1.y, a1.z, a1.w};
#pragma unroll
        for (int b = 0; b < 8; ++b) {
            acc[b][0] = fmaf(av[b], w0.x, acc[b][0]);
            acc[b][1] = fmaf(av[b], w0.y, acc[b][1]);
            acc[b][2] = fmaf(av[b], w0.z, acc[b][2]);
            acc[b][3] = fmaf(av[b], w0.w, acc[b][3]);
            acc[b][4] = fmaf(av[b], w1.x, acc[b][4]);
            acc[b][5] = fmaf(av[b], w1.y, acc[b][5]);
            acc[b][6] = fmaf(av[b], w1.z, acc[b][6]);
            acc[b][7] = fmaf(av[b], w1.w, acc[b][7]);
        }
    }
}

// Grid: 1024 blocks = 2 (j) x 16 (f-tile of 512) x 32 (K-chunk s of 256 rows).
// Block = 256 threads (4 waves), 4 blocks/CU. Wave w owns batches [w*8,+8); lane owns
// 8 consecutive f (F_L=8 halves wave-rows -> LDS broadcast reads fit under VALU).
// ws streams global->registers directly (NO LDS for the 512 MB stream). in-values
// staged ONCE per block into itile[4][256][8] (32 KB) via global_load_lds; each wave
// reads only its own section -> zero barriers; ds(lgkmcnt) decoupled from ws(vmcnt).
// Per wave-row: 64 v_fma (128 cyc) vs 2 global float4 + 2 ds_read_b128 broadcasts.
__global__ __launch_bounds__(256, 4) void gemm_partial(const float* __restrict__ in_t2,
                                                       const float* __restrict__ wsm,
                                                       ushort_t* __restrict__ partial) {
    __shared__ float itile[4][256][8];   // 32 KB

    int lin = blockIdx.x;
    int s   = lin & (NSPLIT - 1);
    int ft  = (lin >> 5) & 15;
    int j   = lin >> 9;
    int w    = __builtin_amdgcn_readfirstlane((int)(threadIdx.x >> 6));
    int lane = threadIdx.x & 63;
    int f0   = ft * 512 + lane * 8;
    int k0   = s * 256;

    // stage this wave's in-slice (256 rows x 8 b = 8 KB, contiguous) via DMA
    const float* isrc = in_t2 + ((size_t)(j * 4 + w) * 8192 + k0) * 8 + lane * 4;
#pragma unroll
    for (int i = 0; i < 8; ++i)
        __builtin_amdgcn_global_load_lds(
            (const __attribute__((address_space(1))) void*)(isrc + i * 256),
            (__attribute__((address_space(3))) void*)&itile[w][i * 32][0], 16, 0, 0);
    asm volatile("s_waitcnt vmcnt(0)" ::: "memory");
    // no barrier needed: each wave reads only its own itile[w]

    const float* __restrict__ wsrow = wsm + ((size_t)j * 8192 + k0) * 8192 + f0;
    const float(*it)[8] = itile[w];

    float acc[8][8];
#pragma unroll
    for (int b = 0; b < 8; ++b)
#pragma unroll
        for (int q = 0; q < 8; ++q) acc[b][q] = 0.f;

    // W granule = 2 rows x 8 f: [row0 f0..3, row0 f4..7, row1 f0..3, row1 f4..7]
#define WLOAD(W, R)                                                        \
    {                                                                      \
        const float* p_ = wsrow + (size_t)(R) * 8192;                      \
        W[0] = *(const float4*)(p_);                                       \
        W[1] = *(const float4*)(p_ + 4);                                   \
        W[2] = *(const float4*)(p_ + 8192);                                \
        W[3] = *(const float4*)(p_ + 8192 + 4);                            \
    }

    float4 WA[4], WB[4];
    WLOAD(WA, 0);
#pragma unroll 1
    for (int r = 0; r < 256; r += 4) {
        WLOAD(WB, r + 2);                 // rows r+2, r+3 in flight
        fma2(acc, it, r, WA);             // rows r, r+1
        WLOAD(WA, (r + 4) & 255);         // rows r+4, r+5 (wraps harmlessly at end)
        fma2(acc, it, r + 2, WB);         // rows r+2, r+3
    }
#undef WLOAD

    // partial[j][s][b][f] in bf16: pack 8 f-values into uint4 (16 B), coalesced
    size_t pbase = ((size_t)((j * NSPLIT + s) * 32 + w * 8)) * 8192 + f0;
#pragma unroll
    for (int b = 0; b < 8; ++b) {
        uint_t p0 = (uint_t)f2bf(acc[b][0]) | ((uint_t)f2bf(acc[b][1]) << 16);
        uint_t p1 = (uint_t)f2bf(acc[b][2]) | ((uint_t)f2bf(acc[b][3]) << 16);
        uint_t p2 = (uint_t)f2bf(acc[b][4]) | ((uint_t)f2bf(acc[b][5]) << 16);
        uint_t p3 = (uint_t)f2bf(acc[b][6]) | ((uint_t)f2bf(acc[b][7]) << 16);
        uint4 v; v.x = p0; v.y = p1; v.z = p2; v.w = p3;
        *(uint4*)(partial + pbase + (size_t)b * 8192) = v;
    }
}

__device__ __forceinline__ float sigmoidf_(float v) { return 1.f / (1.f + expf(-v)); }
__device__ __forceinline__ float bf2f(ushort_t u) {
    uint_t x = ((uint_t)u) << 16;
    return *reinterpret_cast<float*>(&x);
}

// 131072 threads: tid -> (j, b, un)
__global__ __launch_bounds__(256) void epilogue(const ushort_t* __restrict__ partial,
                                                const float* __restrict__ cs,
                                                float* __restrict__ out) {
    int tid = blockIdx.x * 256 + threadIdx.x;
    int un  = tid & 2047;
    int b   = (tid >> 11) & 31;
    int j   = tid >> 16;

    float g4[4];
#pragma unroll
    for (int gate = 0; gate < 4; ++gate) {
        int f = gate * 2048 + un;
        float sum = 0.f;
#pragma unroll
        for (int s = 0; s < NSPLIT; ++s)
            sum += bf2f(partial[((size_t)((j * NSPLIT + s) * 32 + b)) * 8192 + f]);
        g4[gate] = sum;
    }
    float iv = sigmoidf_(g4[0]);
    float fv = sigmoidf_(g4[1]);
    float gv = tanhf(g4[2]);
    float ov = sigmoidf_(g4[3]);
    float ig = iv * gv;

#pragma unroll
    for (int kk = 0; kk < 4; ++kk) {
        float c_old = cs[((j * 4 + kk) * 32 + b) * 2048 + un];
        float c_new = fv * c_old + ig;
        float h     = ov * tanhf(c_new);
        out[393216 + ((j * 4 + kk) * 32 + b) * 2048 + un] = c_new;   // new_c
        if (kk == 0) {
            out[b * 4096 + j * 2048 + un] = h;                       // x_out
        }
        if (kk == j + 2) {
            // new_hs[jj][j][b][un] = h for jj in {0,1}
            out[131072 + ((0 * 2 + j) * 32 + b) * 2048 + un] = h;
            out[131072 + ((1 * 2 + j) * 32 + b) * 2048 + un] = h;
        }
    }
}

extern "C" void kernel_launch(void* const* d_in, const int* in_sizes, int n_in,
                              void* d_out, int out_size, void* d_ws, size_t ws_size,
                              hipStream_t stream) {
    const float* x   = (const float*)d_in[0];
    const float* hs  = (const float*)d_in[1];
    const float* cs  = (const float*)d_in[2];
    const float* wsm = (const float*)d_in[3];
    float* out = (float*)d_out;

    float* in_t2      = (float*)d_ws;                                     // 2 MB
    ushort_t* partial = (ushort_t*)((char*)d_ws + (size_t)IN_T_ELEMS * 4); // 33.5 MB bf16

    transpose_in<<<524288 / 256, 256, 0, stream>>>(x, hs, in_t2);
    gemm_partial<<<1024, 256, 0, stream>>>(in_t2, wsm, partial);
    epilogue<<<131072 / 256, 256, 0, stream>>>(partial, cs, out);
}

// Round 10
// 167.125 us; speedup vs baseline: 1.2039x; 1.2039x over previous
//
#include <hip/hip_runtime.h>
#include <hip/hip_bf16.h>
#include <math.h>

// Problem constants: B=32, U=4096, K=4, N=2, K2=2, STRIDE=2048, UN=2048
// ws: (2, 4, 2048, 8192) f32 = 512 MB  -> the traffic floor
// GEMM per j: (32 x 8192) @ (8192 x 8192), f32 vector-FMA (no fp32 MFMA on CDNA4)
//
// HYPOTHESIS UNDER TEST (r10): HBM read efficiency is chunk-size-bound.
// r2..r9 all read ws in 1 KB chunks strided 32 KB -> ~3.9-4.4 TB/s (62-70%).
// This round: 4 KB contiguous chunks per row (f-tile 1024), same proven DMA+LDS
// machinery as r6. If right -> ~5.5-6 TB/s on the gemm dispatch.
//
// d_out layout (flat, return order):
//   x_out  [0,      131072)   (32,4096)
//   new_hs [131072, 393216)   (2,2,32,2048)
//   new_c  [393216, 917504)   (2,4,32,2048)
//
// d_ws layout:
//   in_t3   at byte 0    : 2*8*8192*4 f32 = 2 MB        (in_t3[j][bg][k][b'], b = bg*4+b')
//   partial at byte 2 MB : 2*32*32*8192 bf16 = 33.5 MB  (partial[j][s][b][f], bf16)

#define IN_T_ELEMS (2 * 8 * 8192 * 4)
#define NSPLIT 32

typedef unsigned short ushort_t;
typedef unsigned int uint_t;

// tid -> b'=tid&3, k=(tid>>2)&8191, bg=(tid>>15)&7, j=tid>>18; b = bg*4+b'
__global__ __launch_bounds__(256) void transpose_in(const float* __restrict__ x,
                                                    const float* __restrict__ hs,
                                                    float* __restrict__ in_t3) {
    int tid = blockIdx.x * 256 + threadIdx.x;   // [0, 524288)
    int bp  = tid & 3;
    int k   = (tid >> 2) & 8191;
    int bg  = (tid >> 15) & 7;
    int j   = tid >> 18;
    int b   = bg * 4 + bp;
    float v;
    if (k < 4096) {
        v = x[b * 4096 + k];                          // x_chunks[b][kk][d] = x[b][k]
    } else {
        int kk = k >> 11;                             // 2 or 3
        int d  = k & 2047;
        v = hs[((j * 2 + (kk - 2)) * 32 + b) * 2048 + d];   // hs (2,2,32,2048)
    }
    in_t3[tid] = v;
}

__device__ __forceinline__ ushort_t f2bf(float x) {
    __hip_bfloat16 h = __float2bfloat16(x);           // round-to-nearest
    return *reinterpret_cast<ushort_t*>(&h);
}

// Grid: 512 blocks = 2 (j) x 8 (f-tile of 1024) x 32 (K-chunk s of 256 rows).
// Block = 512 threads (8 waves), 2 blocks/CU (LDS 64 KB). Wave w owns batches
// [4w, 4w+4); lane owns 16 f as 4 float4s at stride 256 (ds addr = lane*16, the
// proven conflict-free pattern). Each ws row is read as ONE 4 KB contiguous span.
// ws: global_load_lds DMA into double-buffered wtile[2][4][1024], 4-row stages,
// one __syncthreads per stage (r6-proven). in: each wave DMAs its own 4 KB slice
// into itile[w] once at start (wave-private -> no barrier needed for it).
__global__ __launch_bounds__(512, 2) void gemm_partial(const float* __restrict__ in_t3,
                                                       const float* __restrict__ wsm,
                                                       ushort_t* __restrict__ partial) {
    __shared__ float wtile[2][4][1024];   // 32 KB
    __shared__ float itile[8][256][4];    // 32 KB

    int lin = blockIdx.x;                 // [0, 512)
    int s   = lin & (NSPLIT - 1);
    int ft  = (lin >> 5) & 7;
    int j   = lin >> 8;
    int w    = __builtin_amdgcn_readfirstlane((int)(threadIdx.x >> 6));   // 0..7
    int lane = threadIdx.x & 63;
    int k0   = s * 256;
    int fb   = ft * 1024;

#define GLDS16(GP, LP)                                                          \
    __builtin_amdgcn_global_load_lds(                                           \
        (const __attribute__((address_space(1))) void*)(GP),                    \
        (__attribute__((address_space(3))) void*)(LP), 16, 0, 0)

    // ---- itile: wave w stages its own 256x4 slice (4 KB contiguous, 4 DMA) ----
    const float* isrc = in_t3 + ((size_t)(j * 8 + w) * 8192 + k0) * 4 + lane * 4;
#pragma unroll
    for (int i = 0; i < 4; ++i)
        GLDS16(isrc + i * 256, &itile[w][i * 64][0]);

    // ---- ws stage: rows k0+4T..+3; wave w DMAs row (w>>1), half (w&1) (2x 1 KB) ----
    const float* wsrc = wsm + ((size_t)j * 8192 + k0 + (w >> 1)) * 8192
                        + fb + (w & 1) * 512 + lane * 4;
#define STAGE_ISSUE(T)                                                          \
    do {                                                                        \
        int buf_ = (T) & 1;                                                     \
        const float* gp_ = wsrc + (size_t)(T) * 4 * 8192;                       \
        GLDS16(gp_,       &wtile[buf_][w >> 1][(w & 1) * 512]);                 \
        GLDS16(gp_ + 256, &wtile[buf_][w >> 1][(w & 1) * 512 + 256]);           \
    } while (0)

    float4 acc[4][4];
#pragma unroll
    for (int b = 0; b < 4; ++b)
#pragma unroll
        for (int q = 0; q < 4; ++q) acc[b][q] = make_float4(0.f, 0.f, 0.f, 0.f);

    STAGE_ISSUE(0);
    __syncthreads();          // drains vmcnt(0): itile + stage 0 resident

    int l4 = lane * 4;
#pragma unroll 1
    for (int t = 0; t < 64; ++t) {
        if (t + 1 < 64) STAGE_ISSUE(t + 1);    // in flight across this compute phase
        const float(*wt)[1024] = wtile[t & 1];
#pragma unroll
        for (int r = 0; r < 4; ++r) {
            const float* wr = &wt[r][l4];
            float4 wq0 = *(const float4*)(wr);
            float4 wq1 = *(const float4*)(wr + 256);
            float4 wq2 = *(const float4*)(wr + 512);
            float4 wq3 = *(const float4*)(wr + 768);
            float4 av  = *(const float4*)&itile[w][t * 4 + r][0];   // broadcast
            float a;
#pragma unroll
            for (int b = 0; b < 4; ++b) {
                a = (b == 0) ? av.x : (b == 1) ? av.y : (b == 2) ? av.z : av.w;
                acc[b][0].x = fmaf(a, wq0.x, acc[b][0].x);
                acc[b][0].y = fmaf(a, wq0.y, acc[b][0].y);
                acc[b][0].z = fmaf(a, wq0.z, acc[b][0].z);
                acc[b][0].w = fmaf(a, wq0.w, acc[b][0].w);
                acc[b][1].x = fmaf(a, wq1.x, acc[b][1].x);
                acc[b][1].y = fmaf(a, wq1.y, acc[b][1].y);
                acc[b][1].z = fmaf(a, wq1.z, acc[b][1].z);
                acc[b][1].w = fmaf(a, wq1.w, acc[b][1].w);
                acc[b][2].x = fmaf(a, wq2.x, acc[b][2].x);
                acc[b][2].y = fmaf(a, wq2.y, acc[b][2].y);
                acc[b][2].z = fmaf(a, wq2.z, acc[b][2].z);
                acc[b][2].w = fmaf(a, wq2.w, acc[b][2].w);
                acc[b][3].x = fmaf(a, wq3.x, acc[b][3].x);
                acc[b][3].y = fmaf(a, wq3.y, acc[b][3].y);
                acc[b][3].z = fmaf(a, wq3.z, acc[b][3].z);
                acc[b][3].w = fmaf(a, wq3.w, acc[b][3].w);
            }
        }
        __syncthreads();      // buf (t+1) resident; everyone done reading buf t
    }
#undef STAGE_ISSUE
#undef GLDS16

    // partial[j][s][b][f] bf16: b = 4w+bi, f = fb + q*256 + lane*4 -> uint2 stores
    size_t pbase = ((size_t)((j * NSPLIT + s) * 32 + w * 4)) * 8192 + fb + l4;
#pragma unroll
    for (int bi = 0; bi < 4; ++bi) {
#pragma unroll
        for (int q = 0; q < 4; ++q) {
            uint_t p0 = (uint_t)f2bf(acc[bi][q].x) | ((uint_t)f2bf(acc[bi][q].y) << 16);
            uint_t p1 = (uint_t)f2bf(acc[bi][q].z) | ((uint_t)f2bf(acc[bi][q].w) << 16);
            uint2 v; v.x = p0; v.y = p1;
            *(uint2*)(partial + pbase + (size_t)bi * 8192 + q * 256) = v;
        }
    }
}

__device__ __forceinline__ float sigmoidf_(float v) { return 1.f / (1.f + expf(-v)); }
__device__ __forceinline__ float bf2f(ushort_t u) {
    uint_t x = ((uint_t)u) << 16;
    return *reinterpret_cast<float*>(&x);
}

// 131072 threads: tid -> (j, b, un)
__global__ __launch_bounds__(256) void epilogue(const ushort_t* __restrict__ partial,
                                                const float* __restrict__ cs,
                                                float* __restrict__ out) {
    int tid = blockIdx.x * 256 + threadIdx.x;
    int un  = tid & 2047;
    int b   = (tid >> 11) & 31;
    int j   = tid >> 16;

    float g4[4];
#pragma unroll
    for (int gate = 0; gate < 4; ++gate) {
        int f = gate * 2048 + un;
        float sum = 0.f;
#pragma unroll
        for (int s = 0; s < NSPLIT; ++s)
            sum += bf2f(partial[((size_t)((j * NSPLIT + s) * 32 + b)) * 8192 + f]);
        g4[gate] = sum;
    }
    float iv = sigmoidf_(g4[0]);
    float fv = sigmoidf_(g4[1]);
    float gv = tanhf(g4[2]);
    float ov = sigmoidf_(g4[3]);
    float ig = iv * gv;

#pragma unroll
    for (int kk = 0; kk < 4; ++kk) {
        float c_old = cs[((j * 4 + kk) * 32 + b) * 2048 + un];
        float c_new = fv * c_old + ig;
        float h     = ov * tanhf(c_new);
        out[393216 + ((j * 4 + kk) * 32 + b) * 2048 + un] = c_new;   // new_c
        if (kk == 0) {
            out[b * 4096 + j * 2048 + un] = h;                       // x_out
        }
        if (kk == j + 2) {
            // new_hs[jj][j][b][un] = h for jj in {0,1}
            out[131072 + ((0 * 2 + j) * 32 + b) * 2048 + un] = h;
            out[131072 + ((1 * 2 + j) * 32 + b) * 2048 + un] = h;
        }
    }
}

extern "C" void kernel_launch(void* const* d_in, const int* in_sizes, int n_in,
                              void* d_out, int out_size, void* d_ws, size_t ws_size,
                              hipStream_t stream) {
    const float* x   = (const float*)d_in[0];
    const float* hs  = (const float*)d_in[1];
    const float* cs  = (const float*)d_in[2];
    const float* wsm = (const float*)d_in[3];
    float* out = (float*)d_out;

    float* in_t3      = (float*)d_ws;                                      // 2 MB
    ushort_t* partial = (ushort_t*)((char*)d_ws + (size_t)IN_T_ELEMS * 4); // 33.5 MB bf16

    transpose_in<<<524288 / 256, 256, 0, stream>>>(x, hs, in_t3);
    gemm_partial<<<512, 512, 0, stream>>>(in_t3, wsm, partial);
    epilogue<<<131072 / 256, 256, 0, stream>>>(partial, cs, out);
}